// Round 2
// 267.656 us; speedup vs baseline: 1.0495x; 1.0495x over previous
//
#include <hip/hip_runtime.h>
#include <math.h>

#define NTOT   32000      // total nodes
#define NNODE  2000       // nodes per graph
#define NB     16         // batch (graphs)
#define FIN    128        // input features
#define HCDIM  256        // heads*channels
#define NH     4          // heads
#define FC1DIM 512
#define FC2DIM 128
#define FCIN   12000      // 6*NNODE
#define KC1    50         // fc1 k-rows per block
#define NCH1   240        // 12000/KC1
#define CAP    64         // padded adjacency capacity per node (deg ~ Poisson(12))
#define BK     32
#define LPITCH 40         // LDS row pitch in bf16 (80B: 16B-aligned, bank-spread)
#define TRB    384        // (HCDIM*FIN + HCDIM*HCDIM)/256 transpose blocks
#define DEMOB  375        // NB*3*NNODE/256 demo blocks

typedef __attribute__((ext_vector_type(8))) short bf16x8;
typedef __attribute__((ext_vector_type(4))) float f32x4;

// ---------- small helpers ----------
__device__ inline float4 ld4(const float* p){ return *reinterpret_cast<const float4*>(p); }
__device__ inline void st4(float* p, float4 v){ *reinterpret_cast<float4*>(p) = v; }
__device__ inline float4 add4(float4 a, float4 b){ return make_float4(a.x+b.x,a.y+b.y,a.z+b.z,a.w+b.w); }
__device__ inline float lrelu(float x){ return x > 0.f ? x : 0.2f*x; }
__device__ inline float4 leaky4(float4 a){ return make_float4(lrelu(a.x),lrelu(a.y),lrelu(a.z),lrelu(a.w)); }
__device__ inline float4 exp4u(float4 a){ return make_float4(__expf(a.x),__expf(a.y),__expf(a.z),__expf(a.w)); }
__device__ inline float dot4(float4 a, float4 b){ return a.x*b.x + a.y*b.y + a.z*b.z + a.w*b.w; }
__device__ inline float selh(float4 v, int h){ return h==0 ? v.x : (h==1 ? v.y : (h==2 ? v.z : v.w)); }

__device__ inline unsigned short f2bf(float f){
  unsigned int u = __float_as_uint(f);
  u += 0x7FFFu + ((u >> 16) & 1u);
  return (unsigned short)(u >> 16);
}
__device__ inline unsigned int pk2bf(float a, float b){
  return (unsigned int)f2bf(a) | ((unsigned int)f2bf(b) << 16);
}
__device__ inline float bf2f(unsigned short h){
  return __uint_as_float(((unsigned int)h) << 16);
}
__device__ inline float4 ldbf4(const unsigned short* p){
  ushort4 v = *reinterpret_cast<const ushort4*>(p);
  return make_float4(bf2f(v.x), bf2f(v.y), bf2f(v.z), bf2f(v.w));
}

// ---------- zero the adjacency counters (no hipMemsetAsync: graph-capture-safe) ----------
__global__ __launch_bounds__(256) void k_zero(int* __restrict__ cnt){
  int i = blockIdx.x*256 + threadIdx.x;
  if(i < NTOT) cnt[i] = 0;
}

// ---------- layernorm over one graph's 2000 values (one 256-thr block) ----------
__device__ __forceinline__ void ln_impl(const float* __restrict__ src,
                                        const float* __restrict__ lnw,
                                        const float* __restrict__ lnb,
                                        float* __restrict__ o1,
                                        float* __restrict__ o2,
                                        float* __restrict__ o3,
                                        float* red){
  int tid = threadIdx.x, lane = tid & 63, wv = tid >> 6;
  float s = 0.f, ss = 0.f;
  for(int i = tid; i < NNODE; i += 256){ float v = src[i]; s += v; ss += v*v; }
  #pragma unroll
  for(int off=1; off<64; off<<=1){ s += __shfl_xor(s, off); ss += __shfl_xor(ss, off); }
  if(lane == 0){ red[wv] = s; red[4+wv] = ss; }
  __syncthreads();
  s  = red[0]+red[1]+red[2]+red[3];
  ss = red[4]+red[5]+red[6]+red[7];
  float mu  = s * (1.0f/NNODE);
  float var = ss * (1.0f/NNODE) - mu*mu;
  float inv = 1.0f / sqrtf(var + 1e-5f);
  for(int i = tid; i < NNODE; i += 256){
    float v = (src[i]-mu)*inv*lnw[i] + lnb[i];
    o1[i] = v; o2[i] = v; o3[i] = v;
  }
}

// ---------- misc: adjacency build | W transposes | demo fill | x row-means ----------
// (k_prep folded in; xb removed — GEMM-1 converts f32->bf16 in its own staging,
//  so the bf16 copy of x never exists.)
__global__ void k_misc(const int* __restrict__ src, const int* __restrict__ dst,
                       int* __restrict__ cnt, int* __restrict__ col, int e0, int eb,
                       const float* __restrict__ W1, const float* __restrict__ W2,
                       unsigned short* __restrict__ W1t, unsigned short* __restrict__ W2t,
                       const float* __restrict__ sexemb, const float* __restrict__ mutemb,
                       const float* __restrict__ agew, const float* __restrict__ ageb,
                       const float* __restrict__ age, const int* __restrict__ sex,
                       const int* __restrict__ mut, float* __restrict__ t,
                       const float* __restrict__ x, float* __restrict__ x0r){
  int blk = blockIdx.x;
  if(blk < eb){                                   // ---- adjacency build
    int i = blk*256 + threadIdx.x;
    if(i < e0){
      int d = dst[i];
      int slot = atomicAdd(&cnt[d], 1);
      if(slot < CAP) col[(d<<6) + slot] = src[i];
    }
  } else if(blk < eb + TRB){                      // ---- weight transposes + bf16
    int idx = (blk - eb)*256 + threadIdx.x;
    if(idx < HCDIM*FIN){
      int n = idx / FIN, k = idx - n*FIN;
      W1t[idx] = f2bf(W1[(size_t)k*HCDIM + n]);
    } else {
      int j = idx - HCDIM*FIN;
      int n = j / HCDIM, k = j - n*HCDIM;
      W2t[j] = f2bf(W2[(size_t)k*HCDIM + n]);
    }
  } else if(blk < eb + TRB + DEMOB){              // ---- demographic part of t
    int i = (blk - eb - TRB)*256 + threadIdx.x;
    int b = i / (3*NNODE);
    int j = i - b*(3*NNODE);
    float v;
    if(j < NNODE)          v = sexemb[sex[b]*NNODE + j];
    else if(j < 2*NNODE)   v = mutemb[mut[b]*NNODE + (j - NNODE)];
    else                   v = age[b]*agew[j - 2*NNODE] + ageb[j - 2*NNODE];
    t[b*FCIN + j] = v;
  } else {                                        // ---- x0 = mean(x,-1): one wave/row
    int lane = threadIdx.x & 63, wv = threadIdx.x >> 6;
    int n = (blk - eb - TRB - DEMOB)*4 + wv;
    const float* r = x + (size_t)n*FIN;
    float2 v = *reinterpret_cast<const float2*>(r + lane*2);
    float s = v.x + v.y;
    #pragma unroll
    for(int off=1; off<64; off<<=1) s += __shfl_xor(s, off);
    if(lane == 0) x0r[n] = s * (1.0f/FIN);
  }
}

// ---------- bf16 MFMA GEMM + fused attention coefficients ----------
// C[M,256] = A[M,K] @ Bt[256,K]^T. 128x128 tile, 4 waves, 64x64 quadrant each.
// AF32: A is f32 in global; converted to bf16 in-register during LDS staging
// (identical rounding to the old precomputed xb — numerics unchanged).
template<int AF32>
__global__ __launch_bounds__(256) void k_gemm_bf(const void* __restrict__ Av,
                                                 const unsigned short* __restrict__ Bt,
                                                 unsigned short* __restrict__ C,
                                                 const float* __restrict__ attS,
                                                 const float* __restrict__ attD,
                                                 float* __restrict__ a_s,
                                                 float* __restrict__ a_d,
                                                 int M, int K){
  const unsigned short* A = (const unsigned short*)Av;
  const float*         Af = (const float*)Av;
  __shared__ unsigned short As[128][LPITCH];
  __shared__ unsigned short Bs[128][LPITCH];
  int tid = threadIdx.x;
  int lane = tid & 63, wv = tid >> 6;
  int wm = (wv & 1)*64, wn = (wv >> 1)*64;
  int m0 = blockIdx.y*128, n0 = blockIdx.x*128;
  int l15 = lane & 15, lq = lane >> 4;
  f32x4 acc[4][4];
  #pragma unroll
  for(int i=0;i<4;i++)
    #pragma unroll
    for(int j=0;j<4;j++)
      acc[i][j] = (f32x4){0.f,0.f,0.f,0.f};

  int r = tid >> 2, c = (tid & 3)*8;
  for(int k0 = 0; k0 < K; k0 += BK){
    if(AF32){
      const float* pa  = Af + (size_t)(m0+r)*K + k0 + c;
      const float* pa2 = Af + (size_t)(m0+r+64)*K + k0 + c;
      float4 u0 = ld4(pa),  u1 = ld4(pa+4);
      float4 v0 = ld4(pa2), v1 = ld4(pa2+4);
      uint4 w0, w1;
      w0.x = pk2bf(u0.x,u0.y); w0.y = pk2bf(u0.z,u0.w);
      w0.z = pk2bf(u1.x,u1.y); w0.w = pk2bf(u1.z,u1.w);
      w1.x = pk2bf(v0.x,v0.y); w1.y = pk2bf(v0.z,v0.w);
      w1.z = pk2bf(v1.x,v1.y); w1.w = pk2bf(v1.z,v1.w);
      *reinterpret_cast<uint4*>(&As[r][c])    = w0;
      *reinterpret_cast<uint4*>(&As[r+64][c]) = w1;
    } else {
      *reinterpret_cast<uint4*>(&As[r][c])    = *reinterpret_cast<const uint4*>(A  + (size_t)(m0+r)*K + k0 + c);
      *reinterpret_cast<uint4*>(&As[r+64][c]) = *reinterpret_cast<const uint4*>(A  + (size_t)(m0+r+64)*K + k0 + c);
    }
    *reinterpret_cast<uint4*>(&Bs[r][c])    = *reinterpret_cast<const uint4*>(Bt + (size_t)(n0+r)*K + k0 + c);
    *reinterpret_cast<uint4*>(&Bs[r+64][c]) = *reinterpret_cast<const uint4*>(Bt + (size_t)(n0+r+64)*K + k0 + c);
    __syncthreads();
    bf16x8 af[4], bfr[4];
    #pragma unroll
    for(int i=0;i<4;i++){
      af[i]  = *reinterpret_cast<const bf16x8*>(&As[wm + i*16 + l15][lq*8]);
      bfr[i] = *reinterpret_cast<const bf16x8*>(&Bs[wn + i*16 + l15][lq*8]);
    }
    #pragma unroll
    for(int mi=0;mi<4;mi++)
      #pragma unroll
      for(int ni=0;ni<4;ni++)
        acc[mi][ni] = __builtin_amdgcn_mfma_f32_16x16x32_bf16(af[mi], bfr[ni], acc[mi][ni], 0, 0, 0);
    __syncthreads();
  }
  // C/D layout: col = lane&15, row = (lane>>4)*4 + reg
  #pragma unroll
  for(int mi=0;mi<4;mi++){
    #pragma unroll
    for(int ni=0;ni<4;ni++){
      int cn = n0 + wn + ni*16 + l15;
      #pragma unroll
      for(int rg=0;rg<4;rg++){
        int rm = m0 + wm + mi*16 + lq*4 + rg;
        C[(size_t)rm*HCDIM + cn] = f2bf(acc[mi][ni][rg]);
      }
    }
  }
  // fused attention coefficients: this wave's 64 cols = head (n0+wn)/64
  int head = (n0 + wn) >> 6;
  float avs[4], avd[4];
  #pragma unroll
  for(int ni=0;ni<4;ni++){
    int cc = ni*16 + l15;
    avs[ni] = attS[head*64 + cc];
    avd[ni] = attD[head*64 + cc];
  }
  #pragma unroll
  for(int mi=0;mi<4;mi++){
    #pragma unroll
    for(int rg=0;rg<4;rg++){
      float ps = 0.f, pd = 0.f;
      #pragma unroll
      for(int ni=0;ni<4;ni++){
        float v = acc[mi][ni][rg];
        ps = fmaf(avs[ni], v, ps);
        pd = fmaf(avd[ni], v, pd);
      }
      #pragma unroll
      for(int off=1; off<16; off<<=1){
        ps += __shfl_xor(ps, off);
        pd += __shfl_xor(pd, off);
      }
      if(l15 == 0){
        int rm = m0 + wm + mi*16 + lq*4 + rg;
        a_s[rm*4 + head] = ps;
        a_d[rm*4 + head] = pd;
      }
    }
  }
}

// ---------- fused softmax + aggregation + bias + relu + pool-dot ----------
// Blocks 0..15 piggyback the layernorm of the PREVIOUS pooled vector (x0 for layer-1
// launch, x1 for layer-2 launch) — data ready before this launch, and 16%8==0 keeps
// the XCD swizzle of the agg blocks intact.
template<int STORE>
__global__ __launch_bounds__(256) void k_agg(const unsigned short* __restrict__ hpre,
                                             const float* __restrict__ a_s,
                                             const float* __restrict__ a_d,
                                             const int* __restrict__ cnt,
                                             const int* __restrict__ col,
                                             const float* __restrict__ bias,
                                             const float* __restrict__ pw,
                                             const float* __restrict__ pb,
                                             unsigned short* __restrict__ hout,
                                             float* __restrict__ xraw,
                                             const float* __restrict__ lnsrc,
                                             const float* __restrict__ lnw,
                                             const float* __restrict__ lnb,
                                             float* __restrict__ out,
                                             float* __restrict__ t,
                                             int which){
  __shared__ float4 ew[4][CAP];
  __shared__ int    cols[4][CAP];
  __shared__ float  lred[8];
  int bx = blockIdx.x;
  if(bx < 16){                                    // ---- piggybacked layernorm
    int b = bx;
    ln_impl(lnsrc + b*NNODE, lnw, lnb,
            out + 16 + which*(NB*NNODE) + b*NNODE,
            out + 16 + 3*(NB*NNODE) + b*(3*NNODE) + which*NNODE,
            t + b*FCIN + 3*NNODE + which*NNODE, lred);
    return;
  }
  int tid = threadIdx.x;
  int lane = tid & 63, wv = tid >> 6;
  // swizzle: graph g on XCD g%8 so its ~1MB of bf16 hpre rows stays L2-resident
  int blk  = bx - 16;
  int xcd  = blk & 7;
  int slot = blk >> 3;
  int half = slot / 500;
  int g    = xcd + 8*half;
  int n    = g*NNODE + (slot - half*500)*4 + wv;
  int f0 = lane*4;
  int hl = lane >> 4;
  float4 ad   = ld4(a_d + n*4);
  float4 asn  = ld4(a_s + n*4);
  float4 eself = exp4u(leaky4(add4(asn, ad)));   // unnormalized self weight
  int deg = min(cnt[n], CAP);
  int base = n << 6;
  if(lane < deg){
    int s = col[base + lane];
    cols[wv][lane] = s;
    ew[wv][lane] = exp4u(leaky4(add4(ld4(a_s + s*4), ad)));
  }
  float es = selh(eself, hl);
  float dsum = es;
  float4 hv = ldbf4(hpre + (size_t)n*HCDIM + f0);
  float4 acc = make_float4(es*hv.x, es*hv.y, es*hv.z, es*hv.w);
  const float* ewf = (const float*)&ew[wv][0];
  const int*   cwf = &cols[wv][0];
  for(int e = 0; e < deg; e++){
    int s = cwf[e];                       // LDS broadcast (wave-uniform)
    float w = ewf[e*4 + hl];
    dsum += w;
    float4 h2 = ldbf4(hpre + (size_t)s*HCDIM + f0);
    acc.x = fmaf(w, h2.x, acc.x); acc.y = fmaf(w, h2.y, acc.y);
    acc.z = fmaf(w, h2.z, acc.z); acc.w = fmaf(w, h2.w, acc.w);
  }
  float invh = 1.0f / (dsum + 1e-16f);
  float4 b4 = ld4(bias + f0);
  acc = make_float4(fmaxf(fmaf(acc.x,invh,b4.x),0.f), fmaxf(fmaf(acc.y,invh,b4.y),0.f),
                    fmaxf(fmaf(acc.z,invh,b4.z),0.f), fmaxf(fmaf(acc.w,invh,b4.w),0.f));
  if(STORE){
    ushort4 hb = make_ushort4(f2bf(acc.x), f2bf(acc.y), f2bf(acc.z), f2bf(acc.w));
    *reinterpret_cast<ushort4*>(hout + (size_t)n*HCDIM + f0) = hb;
  }
  float part = dot4(acc, ld4(pw + f0));
  #pragma unroll
  for(int off=1; off<64; off<<=1) part += __shfl_xor(part, off);
  if(lane == 0) xraw[n] = part + pb[0];
}

// ---------- layernorm of x2 (the only LN that can't be piggybacked earlier) ----------
__global__ __launch_bounds__(256) void k_lnx2(const float* __restrict__ x2r,
                                              const float* __restrict__ lnw,
                                              const float* __restrict__ lnb,
                                              float* __restrict__ out,
                                              float* __restrict__ t){
  __shared__ float red[8];
  int b = blockIdx.x;
  ln_impl(x2r + b*NNODE, lnw, lnb,
          out + 16 + 2*(NB*NNODE) + b*NNODE,
          out + 16 + 3*(NB*NNODE) + b*(3*NNODE) + 2*NNODE,
          t + b*FCIN + 3*NNODE + 2*NNODE, red);
}

// ---------- FC1: 240-way split-K, one partial per block (NO atomics) ----------
__global__ __launch_bounds__(256) void k_fc1p(const float* __restrict__ t,
                                              const float* __restrict__ fw1,
                                              float* __restrict__ partial){
  __shared__ float ts[NB][KC1];
  __shared__ float red[NB][FC1DIM];
  int tid = threadIdx.x;
  int half = tid >> 7;
  int c4 = (tid & 127) * 4;
  int k0 = blockIdx.x * KC1;
  for(int i = tid; i < NB*KC1; i += 256){
    int b = i / KC1, kk = i - b*KC1;
    ts[b][kk] = t[b*FCIN + k0 + kk];
  }
  __syncthreads();
  float4 acc[NB];
  #pragma unroll
  for(int b=0;b<NB;b++) acc[b] = make_float4(0.f,0.f,0.f,0.f);
  for(int kk = half; kk < KC1; kk += 2){
    float4 w = ld4(fw1 + (size_t)(k0+kk)*FC1DIM + c4);
    #pragma unroll
    for(int b=0;b<NB;b++){
      float tv = ts[b][kk];
      acc[b].x = fmaf(tv, w.x, acc[b].x);
      acc[b].y = fmaf(tv, w.y, acc[b].y);
      acc[b].z = fmaf(tv, w.z, acc[b].z);
      acc[b].w = fmaf(tv, w.w, acc[b].w);
    }
  }
  if(half == 1){
    #pragma unroll
    for(int b=0;b<NB;b++) st4(&red[b][c4], acc[b]);
  }
  __syncthreads();
  if(half == 0){
    float* po = partial + (size_t)blockIdx.x*(NB*FC1DIM);
    #pragma unroll
    for(int b=0;b<NB;b++){
      float4 r = ld4(&red[b][c4]);
      st4(po + b*FC1DIM + c4, add4(acc[b], r));
    }
  }
}

// ---------- fc1 partial reduce: 128 blocks, 4 chunk-groups of 60 per element ----------
__global__ __launch_bounds__(256) void k_fc1r(const float* __restrict__ partial,
                                              const float* __restrict__ fb1,
                                              float* __restrict__ t1){
  __shared__ float red[3][64];
  int tid = threadIdx.x;
  int e = blockIdx.x*64 + (tid & 63);
  int g = tid >> 6;
  float s = 0.f;
  for(int c = g*60; c < g*60 + 60; c++) s += partial[(size_t)c*(NB*FC1DIM) + e];
  if(g) red[g-1][tid & 63] = s;
  __syncthreads();
  if(g == 0){
    s += red[0][tid & 63] + red[1][tid & 63] + red[2][tid & 63];
    s += fb1[e & (FC1DIM-1)];
    t1[e] = fmaxf(s, 0.f);
  }
}

// ---------- fc2 + relu + fc3 fused: one block per batch ----------
__global__ __launch_bounds__(128) void k_head2(const float* __restrict__ t1,
                                               const float* __restrict__ fw2,
                                               const float* __restrict__ fb2,
                                               const float* __restrict__ fw3,
                                               const float* __restrict__ fb3,
                                               float* __restrict__ pred){
  __shared__ float red[2];
  int b = blockIdx.x, j = threadIdx.x;
  const float* tr = t1 + b*FC1DIM;
  float s = fb2[j];
  for(int k=0;k<FC1DIM;k++) s = fmaf(tr[k], fw2[k*FC2DIM+j], s);
  s = fmaxf(s, 0.f) * fw3[j];
  #pragma unroll
  for(int off=1; off<64; off<<=1) s += __shfl_xor(s, off);
  int lane = j & 63, wv = j >> 6;
  if(lane == 0) red[wv] = s;
  __syncthreads();
  if(j == 0) pred[b] = red[0] + red[1] + fb3[0];
}

extern "C" void kernel_launch(void* const* d_in, const int* in_sizes, int n_in,
                              void* d_out, int out_size, void* d_ws, size_t ws_size,
                              hipStream_t stream) {
  const float* x       = (const float*)d_in[0];
  const float* W1      = (const float*)d_in[1];
  const float* attS1   = (const float*)d_in[2];
  const float* attD1   = (const float*)d_in[3];
  const float* b1      = (const float*)d_in[4];
  const float* W2      = (const float*)d_in[5];
  const float* attS2   = (const float*)d_in[6];
  const float* attD2   = (const float*)d_in[7];
  const float* b2      = (const float*)d_in[8];
  const float* pw1     = (const float*)d_in[9];
  const float* pb1     = (const float*)d_in[10];
  const float* pw2     = (const float*)d_in[11];
  const float* pb2     = (const float*)d_in[12];
  const float* lnw     = (const float*)d_in[13];
  const float* lnb     = (const float*)d_in[14];
  const float* sexemb  = (const float*)d_in[15];
  const float* mutemb  = (const float*)d_in[16];
  const float* agew    = (const float*)d_in[17];
  const float* ageb    = (const float*)d_in[18];
  const float* fw1     = (const float*)d_in[19];
  const float* fb1     = (const float*)d_in[20];
  const float* fw2     = (const float*)d_in[21];
  const float* fb2     = (const float*)d_in[22];
  const float* fw3     = (const float*)d_in[23];
  const float* fb3     = (const float*)d_in[24];
  const float* age     = (const float*)d_in[25];
  const int*   eidx    = (const int*)d_in[26];
  const int*   sex     = (const int*)d_in[27];
  const int*   mut     = (const int*)d_in[28];
  const int E0 = in_sizes[26] / 2;
  const int* esrc = eidx;
  const int* edst = eidx + E0;

  float* out = (float*)d_out;

  // workspace layout (floats first, then bf16/int) — xb eliminated
  float* w = (float*)d_ws;
  float* a_s  = w;                        // NTOT*NH
  float* a_d  = a_s + NTOT*NH;
  float* x0r  = a_d + NTOT*NH;            // NTOT (x0r/x1r/x2r contiguous)
  float* x1r  = x0r + NTOT;
  float* x2r  = x1r + NTOT;
  float* tbuf = x2r + NTOT;               // NB*FCIN
  float* part = tbuf + NB*FCIN;           // NCH1*NB*FC1DIM
  float* t1   = part + (size_t)NCH1*NB*FC1DIM; // NB*FC1DIM
  unsigned short* hA  = (unsigned short*)(t1 + NB*FC1DIM);  // NTOT*HCDIM bf16
  unsigned short* hB  = hA  + (size_t)NTOT*HCDIM;           // NTOT*HCDIM bf16
  unsigned short* W1t = hB  + (size_t)NTOT*HCDIM;           // HCDIM*FIN bf16
  unsigned short* W2t = W1t + HCDIM*FIN;                    // HCDIM*HCDIM bf16
  int* cnt    = (int*)(W2t + HCDIM*HCDIM);   // NTOT
  int* col    = cnt + NTOT;                  // NTOT*CAP
  (void)ws_size; (void)n_in; (void)out_size;

  const int eb = (E0 + 255)/256;

  // cnt zero (tiny kernel — no runtime memset APIs under graph capture),
  // then misc (build | transposes | demo | x row-means)
  k_zero<<<(NTOT+255)/256, 256, 0, stream>>>(cnt);
  k_misc<<<eb + TRB + DEMOB + NTOT/4, 256, 0, stream>>>(esrc, edst, cnt, col, E0, eb,
                                               W1, W2, W1t, W2t,
                                               sexemb, mutemb, agew, ageb,
                                               age, sex, mut, tbuf, x, x0r);

  // GAT layer 1 (attn fused into GEMM epilogue; f32 A staged+converted in-register)
  k_gemm_bf<1><<<dim3(HCDIM/128, NTOT/128), 256, 0, stream>>>(x, W1t, hA, attS1, attD1, a_s, a_d, NTOT, FIN);
  k_agg<1><<<16 + NTOT/4, 256, 0, stream>>>(hA, a_s, a_d, cnt, col, b1, pw1, pb1, hB, x1r,
                                            x0r, lnw, lnb, out, tbuf, 0);

  // GAT layer 2 (ln(x1) piggybacked on agg blocks 0..15)
  k_gemm_bf<0><<<dim3(HCDIM/128, NTOT/128), 256, 0, stream>>>(hB, W2t, hA, attS2, attD2, a_s, a_d, NTOT, HCDIM);
  k_agg<0><<<16 + NTOT/4, 256, 0, stream>>>(hA, a_s, a_d, cnt, col, b2, pw2, pb2, hB, x2r,
                                            x1r, lnw, lnb, out, tbuf, 1);

  // remaining tail: ln(x2) only
  k_lnx2<<<NB, 256, 0, stream>>>(x2r, lnw, lnb, out, tbuf);

  // FC head
  k_fc1p<<<NCH1, 256, 0, stream>>>(tbuf, fw1, part);
  k_fc1r<<<(NB*FC1DIM)/64, 256, 0, stream>>>(part, fb1, t1);
  k_head2<<<NB, 128, 0, stream>>>(t1, fw2, fb2, fw3, fb3, out);
}